// Round 10
// baseline (206.301 us; speedup 1.0000x reference)
//
#include <hip/hip_runtime.h>
#include <hip/hip_fp16.h>
#include <math.h>

#define N_ENT 100000
#define N_REL 64
#define DIM   128
#define KNB   32
#define BATCH 16384

typedef _Float16 f16;
typedef __attribute__((ext_vector_type(8))) _Float16 f16x8;
typedef __attribute__((ext_vector_type(4))) _Float16 f16x4;
typedef __attribute__((ext_vector_type(4))) float floatx4;

__device__ __forceinline__ int clamp_id(int id) {
    return id < 0 ? 0 : (id > N_ENT - 1 ? N_ENT - 1 : id);
}

// tanh(x) ~= x + x^3*(-1/3) + x^5*(2/15); |err| < 1e-5 for |x| < 0.5 (true here)
__device__ __forceinline__ float poly_tanh(float x) {
    const float x2 = x * x;
    return x * fmaf(x2, fmaf(x2, 0.13333334f, -0.33333334f), 1.0f);
}

// ---------------------------------------------------------------------------
// Kernel S (merged small prep):
//  blocks 0..63:  f16 copies of Wr/W1/W2 (row-major = MFMA W-operand layout)
//  blocks 64..79: REL16 = f16(maxnorm(rel_table)), one wave per row
// ---------------------------------------------------------------------------
__global__ __launch_bounds__(256) void k_small(
    const float* __restrict__ Wr, const float* __restrict__ W1,
    const float* __restrict__ W2, f16* __restrict__ Wr16,
    f16* __restrict__ W116, f16* __restrict__ W216,
    const float* __restrict__ rel, __half2* __restrict__ REL2)
{
    if (blockIdx.x < 64) {
        const int t = blockIdx.x * 256 + threadIdx.x;   // 0..16383
        Wr16[t] = (f16)Wr[t];
        W116[t] = (f16)W1[t];
        W216[t] = (f16)W2[t];
    } else {
        const int lane = threadIdx.x & 63;
        const int row  = (blockIdx.x - 64) * 4 + (threadIdx.x >> 6);
        const float2 x = *(const float2*)(rel + row * DIM + 2 * lane);
        float ss = x.x * x.x + x.y * x.y;
        #pragma unroll
        for (int m = 1; m < 64; m <<= 1) ss += __shfl_xor(ss, m);
        const float s = fminf(1.0f, 1.0f / fmaxf(sqrtf(ss), 1e-12f));
        REL2[row * 64 + lane] = __floats2half2_rn(x.x * s, x.y * s);
    }
}

// ---------------------------------------------------------------------------
// Kernel P: fused maxnorm + GEMM, barrier-free. One wave per 32-row DOUBLE
// strip (2x MLP on the A-stream: 16 loads in flight vs 8 -> ~2x HBM BW).
// Swapped-operand MFMA (w as A, x as B): lane holds 4 consecutive output
// cols of one row -> 8B f16x4 TR stores. Combined table C16[e] = [TR | N].
// ---------------------------------------------------------------------------
__global__ __launch_bounds__(256, 4) void k_pre(
    const float* __restrict__ ent, const f16* __restrict__ B,
    const float* __restrict__ bias, f16* __restrict__ C16)
{
    const int wid  = threadIdx.x >> 6;
    const int lane = threadIdx.x & 63;
    const int ds = blockIdx.x * 4 + wid;            // double-strip 0..3124
    if (ds >= N_ENT / 32) return;
    const int row0 = ds * 32;
    const int mm = lane & 15, quad = lane >> 4;

    const float* __restrict__ src0 = ent + (size_t)(row0 + mm) * DIM + quad * 8;
    const float* __restrict__ src1 = src0 + 16 * DIM;

    float x0[4][8], x1[4][8];
    #pragma unroll
    for (int kt = 0; kt < 4; ++kt) {
        *(float4*)&x0[kt][0] = *(const float4*)(src0 + kt * 32);
        *(float4*)&x0[kt][4] = *(const float4*)(src0 + kt * 32 + 4);
        *(float4*)&x1[kt][0] = *(const float4*)(src1 + kt * 32);
        *(float4*)&x1[kt][4] = *(const float4*)(src1 + kt * 32 + 4);
    }

    float ss0 = 0.0f, ss1 = 0.0f;
    #pragma unroll
    for (int kt = 0; kt < 4; ++kt)
        #pragma unroll
        for (int j = 0; j < 8; ++j) {
            ss0 = fmaf(x0[kt][j], x0[kt][j], ss0);
            ss1 = fmaf(x1[kt][j], x1[kt][j], ss1);
        }
    ss0 += __shfl_xor(ss0, 16); ss0 += __shfl_xor(ss0, 32);
    ss1 += __shfl_xor(ss1, 16); ss1 += __shfl_xor(ss1, 32);
    const float s0 = fminf(1.0f, 1.0f / fmaxf(sqrtf(ss0), 1e-12f));
    const float s1 = fminf(1.0f, 1.0f / fmaxf(sqrtf(ss1), 1e-12f));

    // x-frags (normalized f16) + N-part stores (cols 128..255 of combined row)
    f16* __restrict__ n0 = C16 + (size_t)(row0 + mm) * 256 + 128 + quad * 8;
    f16* __restrict__ n1 = n0 + 16 * 256;
    f16x8 a0[4], a1[4];
    #pragma unroll
    for (int kt = 0; kt < 4; ++kt) {
        f16x8 v0, v1;
        #pragma unroll
        for (int j = 0; j < 8; ++j) {
            v0[j] = (f16)(x0[kt][j] * s0);
            v1[j] = (f16)(x1[kt][j] * s1);
        }
        a0[kt] = v0; a1[kt] = v1;
        *(f16x8*)(n0 + kt * 32) = v0;
        *(f16x8*)(n1 + kt * 32) = v1;
    }

    // MFMA (swapped operands): D[m=col-in-tile][n=row]; lane mm -> row,
    // quad*4+r -> col. W-frags loaded once, used for both strips.
    f16* __restrict__ t0 = C16 + (size_t)(row0 + mm) * 256;
    f16* __restrict__ t1 = t0 + 16 * 256;
    #pragma unroll
    for (int ct = 0; ct < 8; ++ct) {
        f16x8 w[4];
        #pragma unroll
        for (int kt = 0; kt < 4; ++kt)
            w[kt] = *(const f16x8*)(B + (size_t)(ct * 16 + mm) * DIM + kt * 32 + quad * 8);
        floatx4 acc0 = {0.0f, 0.0f, 0.0f, 0.0f};
        floatx4 acc1 = {0.0f, 0.0f, 0.0f, 0.0f};
        #pragma unroll
        for (int kt = 0; kt < 4; ++kt) {
            acc0 = __builtin_amdgcn_mfma_f32_16x16x32_f16(w[kt], a0[kt], acc0, 0, 0, 0);
            acc1 = __builtin_amdgcn_mfma_f32_16x16x32_f16(w[kt], a1[kt], acc1, 0, 0, 0);
        }
        const float4 bb = *(const float4*)(bias + ct * 16 + quad * 4);
        f16x4 o0, o1;
        #pragma unroll
        for (int r = 0; r < 4; ++r) {
            o0[r] = (f16)(acc0[r] + ((const float*)&bb)[r]);
            o1[r] = (f16)(acc1[r] + ((const float*)&bb)[r]);
        }
        *(f16x4*)(t0 + ct * 16 + quad * 4) = o0;
        *(f16x4*)(t1 + ct * 16 + quad * 4) = o1;
    }
}

// ---------------------------------------------------------------------------
// Kernel B: fused score + softmax + aggregate. One wave per batch element.
// Combined table: TR at uint offset e*128+lane, N at e*128+64+lane -> both
// gathers of a neighbor hit the same 512B region. All 64 gathers prefetched.
// ---------------------------------------------------------------------------
__global__ __launch_bounds__(256, 4) void k_sa(
    const int* __restrict__ idx, const int* __restrict__ adj_ent,
    const int* __restrict__ adj_rel, const unsigned int* __restrict__ C32,
    const __half2* __restrict__ REL2,
    __half2* __restrict__ U2, __half2* __restrict__ V2)
{
    const int wid  = threadIdx.x >> 6;
    const int lane = threadIdx.x & 63;
    const int b = blockIdx.x * 4 + wid;

    const int id = clamp_id(idx[b]);
    const unsigned int hr_u = C32[(size_t)id * 128 + lane];
    const unsigned int h_u  = C32[(size_t)id * 128 + 64 + lane];
    const int eL = adj_ent[(size_t)id * KNB + (lane & 31)];
    const int rL = adj_rel[(size_t)id * KNB + (lane & 31)];

    // prefetch all 64 neighbor-row gathers (TR + N), independent
    unsigned int trd[KNB], tnd[KNB];
    #pragma unroll
    for (int k = 0; k < KNB; ++k) {
        const int e = __builtin_amdgcn_readlane(eL, k);
        const unsigned int* __restrict__ rowp = C32 + (size_t)e * 128 + lane;
        trd[k] = rowp[0];
        tnd[k] = rowp[64];
    }

    // phase 1: independent partials p[k]
    const float2 hr = __half22float2(*(const __half2*)&hr_u);
    float p[KNB];
    #pragma unroll
    for (int k = 0; k < KNB; ++k) {
        const int r = __builtin_amdgcn_readlane(rL, k);
        const float2 tr = __half22float2(*(const __half2*)&trd[k]);
        const float2 rn = __half22float2(REL2[r * 64 + lane]);
        p[k] = poly_tanh(hr.x + rn.x) * tr.x + poly_tanh(hr.y + rn.y) * tr.y;
    }

    // transpose-reduce tree: all 32 lane-sums at once
    #pragma unroll
    for (int step = 0; step < 5; ++step) {
        const int half = 16 >> step;
        const int mask = 1 << step;
        const bool hi_lane = (lane & mask) != 0;
        #pragma unroll
        for (int i = 0; i < 16; ++i) {
            if (i >= half) break;
            const float lo = p[i], hi = p[i + half];
            const float send = hi_lane ? lo : hi;
            const float recv = __shfl_xor(send, mask);
            p[i] = (hi_lane ? hi : lo) + recv;
        }
    }
    const float sc = p[0] + __shfl_xor(p[0], 32);   // lane L: score_{L&31}

    // phase 2: softmax over k (scores O(1); no max-subtract needed)
    const float ex = __expf(sc);
    float tt = ex;
    #pragma unroll
    for (int m = 1; m < 32; m <<= 1) tt += __shfl_xor(tt, m);
    const float attL = ex * __builtin_amdgcn_rcpf(tt);

    // phase 3: aggregate from prefetched registers; att as scalar operand
    float nh0 = 0.0f, nh1 = 0.0f;
    #pragma unroll
    for (int k = 0; k < KNB; ++k) {
        const float a = __uint_as_float(
            __builtin_amdgcn_readlane(__float_as_uint(attL), k));
        const float2 t = __half22float2(*(const __half2*)&tnd[k]);
        nh0 = fmaf(a, t.x, nh0);
        nh1 = fmaf(a, t.y, nh1);
    }

    const float2 h = __half22float2(*(const __half2*)&h_u);
    U2[(size_t)b * 64 + lane] = __floats2half2_rn(h.x + nh0, h.y + nh1);
    V2[(size_t)b * 64 + lane] = __floats2half2_rn(h.x * nh0, h.y * nh1);
}

// ---------------------------------------------------------------------------
// Kernel C: out = leaky(U @ W1^T + b1) + leaky(V @ W2^T + b2) via MFMA f16.
// Swapped operands -> lane holds 4 consecutive cols of one row: float4
// stores with perfect 64B segments. 4096 waves (strip x 2-coltile chunk).
// ---------------------------------------------------------------------------
__global__ __launch_bounds__(256, 4) void k_gemm_out(
    const f16* __restrict__ U, const f16* __restrict__ V,
    const f16* __restrict__ W1h, const float* __restrict__ b1,
    const f16* __restrict__ W2h, const float* __restrict__ b2,
    float* __restrict__ out)
{
    const int wid  = threadIdx.x >> 6;
    const int lane = threadIdx.x & 63;
    const int g = blockIdx.x * 4 + wid;              // 0..4095
    const int strip = g >> 2;
    const int ct0 = (g & 3) * 2;
    const int row0 = strip * 16;
    const int mm = lane & 15, quad = lane >> 4;

    f16x8 au[4], av[4];
    #pragma unroll
    for (int kt = 0; kt < 4; ++kt) {
        au[kt] = *(const f16x8*)(U + (size_t)(row0 + mm) * DIM + kt * 32 + quad * 8);
        av[kt] = *(const f16x8*)(V + (size_t)(row0 + mm) * DIM + kt * 32 + quad * 8);
    }

    #pragma unroll
    for (int c = 0; c < 2; ++c) {
        const int ct = ct0 + c;
        floatx4 accU = {0.0f, 0.0f, 0.0f, 0.0f};
        floatx4 accV = {0.0f, 0.0f, 0.0f, 0.0f};
        #pragma unroll
        for (int kt = 0; kt < 4; ++kt) {
            const f16x8 wu = *(const f16x8*)(W1h + (size_t)(ct * 16 + mm) * DIM + kt * 32 + quad * 8);
            const f16x8 wv = *(const f16x8*)(W2h + (size_t)(ct * 16 + mm) * DIM + kt * 32 + quad * 8);
            accU = __builtin_amdgcn_mfma_f32_16x16x32_f16(wu, au[kt], accU, 0, 0, 0);
            accV = __builtin_amdgcn_mfma_f32_16x16x32_f16(wv, av[kt], accV, 0, 0, 0);
        }
        const float4 bb1 = *(const float4*)(b1 + ct * 16 + quad * 4);
        const float4 bb2 = *(const float4*)(b2 + ct * 16 + quad * 4);
        float4 o;
        #pragma unroll
        for (int r = 0; r < 4; ++r) {
            const float xv = accU[r] + ((const float*)&bb1)[r];
            const float yv = accV[r] + ((const float*)&bb2)[r];
            const float lx = xv > 0.0f ? xv : 0.2f * xv;
            const float ly = yv > 0.0f ? yv : 0.2f * yv;
            ((float*)&o)[r] = lx + ly;
        }
        *(float4*)(out + (size_t)(row0 + mm) * DIM + ct * 16 + quad * 4) = o;
    }
}

extern "C" void kernel_launch(void* const* d_in, const int* in_sizes, int n_in,
                              void* d_out, int out_size, void* d_ws, size_t ws_size,
                              hipStream_t stream) {
    (void)in_sizes; (void)n_in; (void)out_size; (void)ws_size;
    const int*   idx     = (const int*)d_in[0];
    const int*   adj_ent = (const int*)d_in[1];
    const int*   adj_rel = (const int*)d_in[2];
    const float* ent     = (const float*)d_in[3];
    const float* rel     = (const float*)d_in[4];
    const float* Wr_w    = (const float*)d_in[5];
    const float* Wr_b    = (const float*)d_in[6];
    const float* W1_w    = (const float*)d_in[7];
    const float* W1_b    = (const float*)d_in[8];
    const float* W2_w    = (const float*)d_in[9];
    const float* W2_b    = (const float*)d_in[10];
    float* out = (float*)d_out;

    char* ws = (char*)d_ws;
    // workspace layout (bytes):
    f16* C16   = (f16*)(ws);                       // 51,200,000 (combined TR|N)
    f16* REL16 = (f16*)(ws + 51200000);            //     16,384
    f16* U16   = (f16*)(ws + 51216384);            //  4,194,304
    f16* V16   = (f16*)(ws + 55410688);            //  4,194,304
    f16* Wr16  = (f16*)(ws + 59604992);            //     32,768
    f16* W116  = (f16*)(ws + 59637760);            //     32,768
    f16* W216  = (f16*)(ws + 59670528);            //     32,768  (total 59,703,296)

    k_small<<<dim3(80), dim3(256), 0, stream>>>(Wr_w, W1_w, W2_w, Wr16, W116, W216,
                                                rel, (__half2*)REL16);
    k_pre<<<dim3((N_ENT / 32 + 3) / 4), dim3(256), 0, stream>>>(ent, Wr16, Wr_b, C16);
    k_sa<<<dim3(BATCH / 4), dim3(256), 0, stream>>>(idx, adj_ent, adj_rel,
                                                    (const unsigned int*)C16,
                                                    (const __half2*)REL16,
                                                    (__half2*)U16, (__half2*)V16);
    k_gemm_out<<<dim3(1024), dim3(256), 0, stream>>>(U16, V16, W116, W1_b,
                                                     W216, W2_b, out);
}